// Round 2
// baseline (500.824 us; speedup 1.0000x reference)
//
#include <hip/hip_runtime.h>
#include <hip/hip_bf16.h>

// GCN forward, MI355X. Inputs may be fp32 or packed-bf16 (and edge/batch
// int32 or int64) depending on how the harness materialized the reference —
// a device-side detect kernel decides, then converters canonicalize into
// bf16 features / int32 indices in d_ws. Same dispatch sequence every call
// (graph-capture safe); branches on the flags are wave-uniform device code.
//
// Pipeline: detect -> canonicalize(x, W/b, edges, batch) -> degree count ->
// single-block scan (row_ptr, cursor, dinv) -> CSR fill -> 4x (GEMM with W
// in LDS -> dst-centric CSR gather fused w/ self-loop+bias+ReLU) ->
// LDS-blocked mean-pool -> tiny final linear (dtype-dispatched store).

#define N_GRAPHS 64
#define N_CLASSES 10
static constexpr int FEAT = 128;

__device__ __forceinline__ float b2f(unsigned int u) {
  return __uint_as_float(u << 16);
}
__device__ __forceinline__ unsigned short f2b(float f) {
  unsigned int x = __float_as_uint(f);
  x += 0x7fffu + ((x >> 16) & 1u);   // RNE (finite values only)
  return (unsigned short)(x >> 16);
}

// flags[0] = 1 if floats are fp32, 0 if packed bf16.
// flags[1] = 1 if ints are int64, 0 if int32.
__global__ __launch_bounds__(256) void detect_kernel(const unsigned int* __restrict__ xraw,
    const unsigned int* __restrict__ eraw, int* __restrict__ flags) {
  __shared__ int cnt_bf16, cnt_i64nz;
  if (threadIdx.x == 0) { cnt_bf16 = 0; cnt_i64nz = 0; }
  __syncthreads();
  unsigned int d = xraw[threadIdx.x];
  unsigned int lo = d & 0xffffu;
  int e = (int)((lo >> 7) & 0xff);
  if (e >= 100 && e <= 140) atomicAdd(&cnt_bf16, 1);
  if (threadIdx.x < 64) {
    if (eraw[2 * threadIdx.x + 1] != 0u) atomicAdd(&cnt_i64nz, 1);
  }
  __syncthreads();
  if (threadIdx.x == 0) {
    flags[0] = (cnt_bf16 < 150) ? 1 : 0;
    flags[1] = (cnt_i64nz == 0) ? 1 : 0;
  }
}

// canonical x: bf16 pairs. n2 = N*FEAT/2 output dwords.
__global__ void cvt_x_kernel(const unsigned int* __restrict__ xraw,
    unsigned int* __restrict__ xc, const int* __restrict__ flags, int n2) {
  int i = blockIdx.x * blockDim.x + threadIdx.x;
  if (i >= n2) return;
  if (flags[0]) {
    const float* xf = (const float*)xraw;
    float a = xf[2 * i], b = xf[2 * i + 1];
    xc[i] = (unsigned int)f2b(a) | ((unsigned int)f2b(b) << 16);
  } else {
    xc[i] = xraw[i];
  }
}

struct WPtrs {
  const void* p[10];
};
static constexpr int WSEG[10]  = {16384, 128, 8192, 64, 2048, 32, 512, 16, 160, 10};
static constexpr int WTOTAL    = 27546;
// canonical element offsets (prefix sums of WSEG):
static constexpr int WOFF[10]  = {0, 16384, 16512, 24704, 24768, 26816, 26848, 27360, 27376, 27536};

__global__ void cvt_w_kernel(WPtrs wp, unsigned short* __restrict__ wc,
                             const int* __restrict__ flags) {
  int i = blockIdx.x * blockDim.x + threadIdx.x;
  if (i >= WTOTAL) return;
  int off = i, s = 0;
  #pragma unroll
  for (int t = 0; t < 10; ++t) {
    if (s == 0 && off >= WSEG[t]) { off -= WSEG[t]; } else if (s == 0) { s = t + 1; }
  }
  s -= 1;
  const void* p = wp.p[s];
  unsigned short v;
  if (flags[0]) v = f2b(((const float*)p)[off]);
  else          v = ((const unsigned short*)p)[off];
  wc[i] = v;
}

__global__ void cvt_edges_kernel(const int* __restrict__ eraw, int* __restrict__ src32,
    int* __restrict__ dst32, const int* __restrict__ flags, int E) {
  int e = blockIdx.x * blockDim.x + threadIdx.x;
  if (e >= E) return;
  if (flags[1]) {
    src32[e] = eraw[2 * e];
    dst32[e] = eraw[2 * (E + e)];
  } else {
    src32[e] = eraw[e];
    dst32[e] = eraw[E + e];
  }
}

__global__ void cvt_batch_kernel(const int* __restrict__ braw, int* __restrict__ b32,
    const int* __restrict__ flags, int n) {
  int i = blockIdx.x * blockDim.x + threadIdx.x;
  if (i >= n) return;
  b32[i] = flags[1] ? braw[2 * i] : braw[i];
}

__global__ void count_kernel(const int* __restrict__ dst, int* __restrict__ cnt, int E) {
  int e = blockIdx.x * blockDim.x + threadIdx.x;
  if (e < E) atomicAdd(&cnt[dst[e]], 1);
}

// Single-block inclusive scan over N counts. 1024 threads, wave-shuffle scan
// + LDS wave-sum combine.
__global__ __launch_bounds__(1024) void scan_kernel(const int* __restrict__ cnt,
    int* __restrict__ row_ptr, int* __restrict__ cursor, float* __restrict__ dinv, int n) {
  __shared__ int wave_sums[16];
  __shared__ int s_base;
  const int tid = threadIdx.x;
  const int lane = tid & 63;
  const int wv = tid >> 6;
  if (tid == 0) { s_base = 0; row_ptr[0] = 0; }
  __syncthreads();
  for (int chunk = 0; chunk < n; chunk += 1024) {
    int i = chunk + tid;
    int v = (i < n) ? cnt[i] : 0;
    int x = v;
    #pragma unroll
    for (int off = 1; off < 64; off <<= 1) {
      int y = __shfl_up(x, off, 64);
      if (lane >= off) x += y;
    }
    if (lane == 63) wave_sums[wv] = x;
    __syncthreads();
    int wbase = 0;
    for (int w = 0; w < wv; ++w) wbase += wave_sums[w];
    int incl = x + wbase;
    int base = s_base;
    __syncthreads();
    if (i < n) {
      row_ptr[i + 1] = base + incl;
      cursor[i] = base + incl - v;
      dinv[i] = rsqrtf((float)v + 1.0f);
    }
    if (tid == 1023) s_base = base + incl;
    __syncthreads();
  }
}

__global__ void fill_kernel(const int* __restrict__ src, const int* __restrict__ dst,
    int* __restrict__ cursor, const float* __restrict__ dinv,
    int* __restrict__ csr_src, float* __restrict__ csr_coef, int E) {
  int e = blockIdx.x * blockDim.x + threadIdx.x;
  if (e < E) {
    int s = src[e], d = dst[e];
    int pos = atomicAdd(&cursor[d], 1);
    csr_src[pos] = s;
    csr_coef[pos] = dinv[s] * dinv[d];
  }
}

// H[n,FOUT] = X[n,FIN] @ W[FIN,FOUT], bf16 in/out, fp32 accumulate.
template<int FIN, int FOUT, int NT>
__global__ __launch_bounds__(256) void gemm_kernel(const unsigned short* __restrict__ X,
    const unsigned short* __restrict__ W, unsigned short* __restrict__ H, int n) {
  constexpr int NPB = NT * 256 / FOUT;
  constexpr int XLD = FIN + 1;
  __shared__ unsigned short Wl[FIN * FOUT];
  __shared__ float Xl[NPB * XLD];
  {
    const ushort4* Wg = (const ushort4*)W;
    ushort4* Ws = (ushort4*)Wl;
    for (int i = threadIdx.x; i < FIN * FOUT / 4; i += 256) Ws[i] = Wg[i];
  }
  const int node0 = blockIdx.x * NPB;
  for (int i = threadIdx.x; i < NPB * FIN / 4; i += 256) {
    int base = i * 4;
    int r = base / FIN, k = base - r * FIN;
    int nd = node0 + r;
    float f0 = 0.f, f1 = 0.f, f2 = 0.f, f3 = 0.f;
    if (nd < n) {
      ushort4 u = ((const ushort4*)(X + (size_t)nd * FIN))[k >> 2];
      f0 = b2f(u.x); f1 = b2f(u.y); f2 = b2f(u.z); f3 = b2f(u.w);
    }
    float* xp = &Xl[r * XLD + k];
    xp[0] = f0; xp[1] = f1; xp[2] = f2; xp[3] = f3;
  }
  __syncthreads();
  const int j = threadIdx.x % FOUT;
  const int grp = threadIdx.x / FOUT;
  float acc[NT];
  #pragma unroll
  for (int t = 0; t < NT; ++t) acc[t] = 0.f;
  #pragma unroll 4
  for (int k = 0; k < FIN; ++k) {
    float w = b2f(Wl[k * FOUT + j]);
    #pragma unroll
    for (int t = 0; t < NT; ++t)
      acc[t] = fmaf(Xl[(grp * NT + t) * XLD + k], w, acc[t]);
  }
  #pragma unroll
  for (int t = 0; t < NT; ++t) {
    int node = node0 + grp * NT + t;
    if (node < n) H[(size_t)node * FOUT + j] = f2b(acc[t]);
  }
}

// OUT[g,:] = relu( sum_{e:dst=g} coef_e*H[src_e,:] + dinv[g]^2*H[g,:] + bias )
template<int F>
__global__ __launch_bounds__(256) void agg_kernel(const unsigned short* __restrict__ H,
    const int* __restrict__ row_ptr, const int* __restrict__ csr_src,
    const float* __restrict__ csr_coef, const float* __restrict__ dinv,
    const unsigned short* __restrict__ bias, unsigned short* __restrict__ OUT, int n) {
  constexpr int LPG = F / 2;
  constexpr int GPB = 256 / LPG;
  const int g = blockIdx.x * GPB + threadIdx.x / LPG;
  const int l = threadIdx.x % LPG;
  if (g >= n) return;
  const unsigned int* H2 = (const unsigned int*)H;
  float di = dinv[g];
  unsigned int hv = H2[(size_t)g * LPG + l];
  float c0 = di * di;
  float ax = b2f(hv & 0xffffu) * c0;
  float ay = b2f(hv >> 16) * c0;
  const int e1 = row_ptr[g + 1];
  for (int e = row_ptr[g]; e < e1; ++e) {
    int s = csr_src[e];
    float c = csr_coef[e];
    unsigned int v = H2[(size_t)s * LPG + l];
    ax = fmaf(b2f(v & 0xffffu), c, ax);
    ay = fmaf(b2f(v >> 16), c, ay);
  }
  unsigned int bb = ((const unsigned int*)bias)[l];
  ax += b2f(bb & 0xffffu);
  ay += b2f(bb >> 16);
  ax = fmaxf(ax, 0.f);
  ay = fmaxf(ay, 0.f);
  ((unsigned int*)OUT)[(size_t)g * LPG + l] = ((unsigned int)f2b(ay) << 16) | f2b(ax);
}

__global__ __launch_bounds__(256) void pool_kernel(const unsigned short* __restrict__ X,
    const int* __restrict__ batch, float* __restrict__ pooled, float* __restrict__ cnt, int n) {
  __shared__ float acc[N_GRAPHS * 16];
  __shared__ float ccnt[N_GRAPHS];
  for (int i = threadIdx.x; i < N_GRAPHS * 16; i += 256) acc[i] = 0.f;
  if (threadIdx.x < N_GRAPHS) ccnt[threadIdx.x] = 0.f;
  __syncthreads();
  const int f = threadIdx.x & 15;
  const int lane = threadIdx.x >> 4;
  const int base = blockIdx.x * 256;
  for (int it = 0; it < 16; ++it) {
    int node = base + it * 16 + lane;
    if (node < n) {
      int g = batch[node];
      float v = b2f(X[(size_t)node * 16 + f]);
      atomicAdd(&acc[g * 16 + f], v);
      if (f == 0) atomicAdd(&ccnt[g], 1.f);
    }
  }
  __syncthreads();
  for (int i = threadIdx.x; i < N_GRAPHS * 16; i += 256)
    if (acc[i] != 0.f) atomicAdd(&pooled[i], acc[i]);
  if (threadIdx.x < N_GRAPHS && ccnt[threadIdx.x] != 0.f)
    atomicAdd(&cnt[threadIdx.x], ccnt[threadIdx.x]);
}

__global__ void final_kernel(const float* __restrict__ pooled, const float* __restrict__ cnt,
    const unsigned short* __restrict__ wc, void* __restrict__ out,
    const int* __restrict__ flags) {
  int id = blockIdx.x * blockDim.x + threadIdx.x;
  if (id >= N_GRAPHS * N_CLASSES) return;
  const unsigned short* Wlin = wc + WOFF[8];
  const unsigned short* blin = wc + WOFF[9];
  int g = id / N_CLASSES, c = id - g * N_CLASSES;
  float inv = 1.0f / fmaxf(cnt[g], 1.0f);
  float a = b2f(blin[c]);
  #pragma unroll
  for (int f = 0; f < 16; ++f)
    a = fmaf(pooled[g * 16 + f] * inv, b2f(Wlin[f * N_CLASSES + c]), a);
  if (flags[0]) ((float*)out)[id] = a;
  else          ((unsigned short*)out)[id] = f2b(a);
}

extern "C" void kernel_launch(void* const* d_in, const int* in_sizes, int n_in,
                              void* d_out, int out_size, void* d_ws, size_t ws_size,
                              hipStream_t stream) {
  const unsigned int* xraw = (const unsigned int*)d_in[0];
  const int* eraw          = (const int*)d_in[1];
  const int* braw          = (const int*)d_in[2];

  const int N = in_sizes[2];
  const int E = in_sizes[1] / 2;

  char* p = (char*)d_ws;
  auto alloc = [&](size_t bytes) -> void* {
    void* r = (void*)p;
    p += (bytes + 255) & ~(size_t)255;
    return r;
  };
  int*   flags    = (int*)  alloc(256);
  int*   deg      = (int*)  alloc((size_t)N * 4);
  int*   row_ptr  = (int*)  alloc((size_t)(N + 1) * 4);
  int*   cursor   = (int*)  alloc((size_t)N * 4);
  float* dinv     = (float*)alloc((size_t)N * 4);
  int*   src32    = (int*)  alloc((size_t)E * 4);
  int*   dst32    = (int*)  alloc((size_t)E * 4);
  int*   batch32  = (int*)  alloc((size_t)N * 4);
  int*   csr_src  = (int*)  alloc((size_t)E * 4);
  float* csr_coef = (float*)alloc((size_t)E * 4);
  unsigned short* wcan = (unsigned short*)alloc((size_t)WTOTAL * 2);
  unsigned short* xcan = (unsigned short*)alloc((size_t)N * FEAT * 2);
  unsigned short* hbuf = (unsigned short*)alloc((size_t)N * FEAT * 2);
  float* pooled = (float*)alloc(N_GRAPHS * 16 * 4);
  float* cntf   = (float*)alloc(N_GRAPHS * 4);

  hipMemsetAsync(deg, 0, (size_t)N * 4, stream);
  hipMemsetAsync(pooled, 0, N_GRAPHS * 16 * 4, stream);
  hipMemsetAsync(cntf, 0, N_GRAPHS * 4, stream);

  const int tb = 256;
  detect_kernel<<<1, 256, 0, stream>>>(xraw, (const unsigned int*)eraw, flags);

  int n2 = N * FEAT / 2;
  cvt_x_kernel<<<(n2 + tb - 1) / tb, tb, 0, stream>>>(xraw, (unsigned int*)xcan, flags, n2);
  WPtrs wp;
  for (int i = 0; i < 10; ++i) wp.p[i] = d_in[3 + i];
  cvt_w_kernel<<<(WTOTAL + tb - 1) / tb, tb, 0, stream>>>(wp, wcan, flags);
  cvt_edges_kernel<<<(E + tb - 1) / tb, tb, 0, stream>>>(eraw, src32, dst32, flags, E);
  cvt_batch_kernel<<<(N + tb - 1) / tb, tb, 0, stream>>>(braw, batch32, flags, N);

  count_kernel<<<(E + tb - 1) / tb, tb, 0, stream>>>(dst32, deg, E);
  scan_kernel<<<1, 1024, 0, stream>>>(deg, row_ptr, cursor, dinv, N);
  fill_kernel<<<(E + tb - 1) / tb, tb, 0, stream>>>(src32, dst32, cursor, dinv, csr_src, csr_coef, E);

  const unsigned short* W1 = wcan + WOFF[0];
  const unsigned short* b1 = wcan + WOFF[1];
  const unsigned short* W2 = wcan + WOFF[2];
  const unsigned short* b2 = wcan + WOFF[3];
  const unsigned short* W3 = wcan + WOFF[4];
  const unsigned short* b3 = wcan + WOFF[5];
  const unsigned short* W4 = wcan + WOFF[6];
  const unsigned short* b4 = wcan + WOFF[7];

  // layer 1: 128 -> 128   (xcan -> hbuf -> xcan)
  gemm_kernel<128, 128, 8><<<(N + 15) / 16, 256, 0, stream>>>(xcan, W1, hbuf, N);
  agg_kernel<128><<<(N + 3) / 4, 256, 0, stream>>>(hbuf, row_ptr, csr_src, csr_coef, dinv, b1, xcan, N);
  // layer 2: 128 -> 64
  gemm_kernel<128, 64, 8><<<(N + 31) / 32, 256, 0, stream>>>(xcan, W2, hbuf, N);
  agg_kernel<64><<<(N + 7) / 8, 256, 0, stream>>>(hbuf, row_ptr, csr_src, csr_coef, dinv, b2, xcan, N);
  // layer 3: 64 -> 32
  gemm_kernel<64, 32, 8><<<(N + 63) / 64, 256, 0, stream>>>(xcan, W3, hbuf, N);
  agg_kernel<32><<<(N + 15) / 16, 256, 0, stream>>>(hbuf, row_ptr, csr_src, csr_coef, dinv, b3, xcan, N);
  // layer 4: 32 -> 16
  gemm_kernel<32, 16, 8><<<(N + 127) / 128, 256, 0, stream>>>(xcan, W4, hbuf, N);
  agg_kernel<16><<<(N + 31) / 32, 256, 0, stream>>>(hbuf, row_ptr, csr_src, csr_coef, dinv, b4, xcan, N);

  pool_kernel<<<(N + 255) / 256, 256, 0, stream>>>(xcan, batch32, pooled, cntf, N);
  final_kernel<<<(N_GRAPHS * N_CLASSES + 127) / 128, 128, 0, stream>>>(pooled, cntf, wcan, d_out, flags);
}

// Round 3
// 312.872 us; speedup vs baseline: 1.6007x; 1.6007x over previous
//
#include <hip/hip_runtime.h>
#include <hip/hip_bf16.h>

// GCN forward, MI355X. Dtype-detecting (fp32-vs-bf16 floats, int64-vs-int32
// indices) with canonicalization into bf16/int32 workspace buffers.
//
// Pipeline: detect -> cvt_x(+batch) -> cvt_w -> cvt_edges(+degree count) ->
// 3-kernel hierarchical scan (row_ptr/cursor/dinv) -> CSR fill ->
// 4x (MFMA GEMM -> vectorized dst-gather agg fused w/ self-loop+bias+ReLU)
// -> LDS-blocked mean-pool -> tiny final linear.
//
// MFMA layout (verified m89/m91/m120): A[m=l&15][k=(l>>4)*8+j] (k-contig ->
// 16B global loads from row-major X); B[k=(l>>4)*8+j][n=l&15] staged in LDS
// fragment-major (frag*1024 + lane*16) so ds_read_b128 is sequential,
// conflict-free; C/D col=l&15, row=(l>>4)*4+reg.

#define N_GRAPHS 64
#define N_CLASSES 10
static constexpr int FEAT = 128;

typedef short bf8_t __attribute__((ext_vector_type(8)));
typedef float f4_t  __attribute__((ext_vector_type(4)));

__device__ __forceinline__ float b2f(unsigned int u) {
  return __uint_as_float(u << 16);
}
__device__ __forceinline__ unsigned short f2b(float f) {
  unsigned int x = __float_as_uint(f);
  x += 0x7fffu + ((x >> 16) & 1u);   // RNE (finite values only)
  return (unsigned short)(x >> 16);
}

// flags[0]=1 if floats fp32 else bf16; flags[1]=1 if ints int64 else int32.
__global__ __launch_bounds__(256) void detect_kernel(const unsigned int* __restrict__ xraw,
    const unsigned int* __restrict__ eraw, int* __restrict__ flags) {
  __shared__ int cnt_bf16, cnt_i64nz;
  if (threadIdx.x == 0) { cnt_bf16 = 0; cnt_i64nz = 0; }
  __syncthreads();
  unsigned int d = xraw[threadIdx.x];
  int e = (int)(((d & 0xffffu) >> 7) & 0xff);
  if (e >= 100 && e <= 140) atomicAdd(&cnt_bf16, 1);
  if (threadIdx.x < 64 && eraw[2 * threadIdx.x + 1] != 0u) atomicAdd(&cnt_i64nz, 1);
  __syncthreads();
  if (threadIdx.x == 0) {
    flags[0] = (cnt_bf16 < 150) ? 1 : 0;
    flags[1] = (cnt_i64nz == 0) ? 1 : 0;
  }
}

__global__ void cvt_x_kernel(const unsigned int* __restrict__ xraw,
    unsigned int* __restrict__ xc, const int* __restrict__ braw,
    int* __restrict__ b32, const int* __restrict__ flags, int n2, int n) {
  int i = blockIdx.x * blockDim.x + threadIdx.x;
  int f32 = flags[0];
  if (i < n2) {
    if (f32) {
      const float* xf = (const float*)xraw;
      xc[i] = (unsigned int)f2b(xf[2 * i]) | ((unsigned int)f2b(xf[2 * i + 1]) << 16);
    } else {
      xc[i] = xraw[i];
    }
  }
  if (i < n) b32[i] = flags[1] ? braw[2 * i] : braw[i];
}

struct WPtrs { const void* p[10]; };
static constexpr int WSEG[10] = {16384, 128, 8192, 64, 2048, 32, 512, 16, 160, 10};
static constexpr int WTOTAL   = 27546;
static constexpr int WOFF[10] = {0, 16384, 16512, 24704, 24768, 26816, 26848, 27360, 27376, 27536};

__global__ void cvt_w_kernel(WPtrs wp, unsigned short* __restrict__ wc,
                             const int* __restrict__ flags) {
  int i = blockIdx.x * blockDim.x + threadIdx.x;
  if (i >= WTOTAL) return;
  int off = i, s = 0;
  #pragma unroll
  for (int t = 0; t < 10; ++t) {
    if (s == 0 && off >= WSEG[t]) { off -= WSEG[t]; } else if (s == 0) { s = t + 1; }
  }
  s -= 1;
  const void* p = wp.p[s];
  wc[i] = flags[0] ? f2b(((const float*)p)[off]) : ((const unsigned short*)p)[off];
}

// edge convert + in-degree count fused
__global__ void cvt_edges_kernel(const int* __restrict__ eraw, int* __restrict__ src32,
    int* __restrict__ dst32, int* __restrict__ deg, const int* __restrict__ flags, int E) {
  int e = blockIdx.x * blockDim.x + threadIdx.x;
  if (e >= E) return;
  int s, d;
  if (flags[1]) { s = eraw[2 * e]; d = eraw[2 * (E + e)]; }
  else          { s = eraw[e];     d = eraw[E + e]; }
  src32[e] = s; dst32[e] = d;
  atomicAdd(&deg[d], 1);
}

// ---- hierarchical scan: deg -> row_ptr/cursor/dinv ----
__device__ __forceinline__ int block_incl_scan(int v, int* wave_sums) {
  const int lane = threadIdx.x & 63;
  const int wv = threadIdx.x >> 6;
  int x = v;
  #pragma unroll
  for (int off = 1; off < 64; off <<= 1) {
    int y = __shfl_up(x, off, 64);
    if (lane >= off) x += y;
  }
  if (lane == 63) wave_sums[wv] = x;
  __syncthreads();
  int wbase = 0;
  for (int w = 0; w < wv; ++w) wbase += wave_sums[w];
  return x + wbase;
}

__global__ __launch_bounds__(256) void scan1_kernel(const int* __restrict__ deg,
    int* __restrict__ partials, int n) {
  __shared__ int ws[4];
  int i = blockIdx.x * 256 + threadIdx.x;
  int v = (i < n) ? deg[i] : 0;
  int incl = block_incl_scan(v, ws);
  if (threadIdx.x == 255) partials[blockIdx.x] = incl;
}

// nb <= 256 (N <= 65536)
__global__ __launch_bounds__(256) void scan2_kernel(int* __restrict__ partials, int nb) {
  __shared__ int ws[4];
  int v = (threadIdx.x < nb) ? partials[threadIdx.x] : 0;
  int incl = block_incl_scan(v, ws);
  if (threadIdx.x < nb) partials[threadIdx.x] = incl - v;  // exclusive
}

__global__ __launch_bounds__(256) void scan3_kernel(const int* __restrict__ deg,
    const int* __restrict__ partials, int* __restrict__ row_ptr, int* __restrict__ cursor,
    float* __restrict__ dinv, int n) {
  __shared__ int ws[4];
  int i = blockIdx.x * 256 + threadIdx.x;
  int v = (i < n) ? deg[i] : 0;
  int incl = block_incl_scan(v, ws) + partials[blockIdx.x];
  if (i < n) {
    row_ptr[i + 1] = incl;
    cursor[i] = incl - v;
    dinv[i] = rsqrtf((float)v + 1.0f);
  }
  if (i == 0) row_ptr[0] = 0;
}

__global__ void fill_kernel(const int* __restrict__ src, const int* __restrict__ dst,
    int* __restrict__ cursor, const float* __restrict__ dinv,
    int* __restrict__ csr_src, float* __restrict__ csr_coef, int E) {
  int e = blockIdx.x * blockDim.x + threadIdx.x;
  if (e < E) {
    int s = src[e], d = dst[e];
    int pos = atomicAdd(&cursor[d], 1);
    csr_src[pos] = s;
    csr_coef[pos] = dinv[s] * dinv[d];
  }
}

// H[n,FOUT] = X[n,FIN] @ W[FIN,FOUT] via v_mfma_f32_16x16x32_bf16.
// Wave = 32 rows (2 m-tiles of 16). W staged in LDS fragment-major.
template<int FIN, int FOUT>
__global__ __launch_bounds__(256) void mfma_gemm_kernel(const unsigned short* __restrict__ X,
    const unsigned short* __restrict__ Wg, unsigned short* __restrict__ H, int n) {
  constexpr int KB = FIN / 32;   // k-blocks per row
  constexpr int CT = FOUT / 16;  // 16-wide col tiles
  __shared__ unsigned short Wt[FIN * FOUT];  // fragment-major
  // LDS short index i = ((ct*KB+kb)*64 + l)*8 + j  holds  W[kb*32+(l>>4)*8+j][ct*16+(l&15)]
  for (int i = threadIdx.x; i < FIN * FOUT; i += 256) {
    int j = i & 7, l = (i >> 3) & 63, f = i >> 9;
    int ct = f / KB, kb = f - ct * KB;
    int k = kb * 32 + (l >> 4) * 8 + j;
    int nn = ct * 16 + (l & 15);
    Wt[i] = Wg[k * FOUT + nn];
  }
  __syncthreads();
  const int l = threadIdx.x & 63;
  const int r16 = l & 15, quad = l >> 4;
  const int m0 = (blockIdx.x * 4 + (threadIdx.x >> 6)) * 32;
  if (m0 >= n) return;
  // A fragments: 2 m-tiles x KB, 16B contiguous global loads
  bf8_t afrag[2][KB];
  #pragma unroll
  for (int mt = 0; mt < 2; ++mt) {
    int node = m0 + mt * 16 + r16;
    int nc = node < n ? node : n - 1;
    const unsigned short* xp = X + (size_t)nc * FIN + quad * 8;
    #pragma unroll
    for (int kb = 0; kb < KB; ++kb)
      afrag[mt][kb] = *(const bf8_t*)(xp + kb * 32);
  }
  #pragma unroll
  for (int ct = 0; ct < CT; ++ct) {
    bf8_t bfrag[KB];
    #pragma unroll
    for (int kb = 0; kb < KB; ++kb)
      bfrag[kb] = *(const bf8_t*)(&Wt[((ct * KB + kb) * 64 + l) * 8]);
    #pragma unroll
    for (int mt = 0; mt < 2; ++mt) {
      f4_t acc = {0.f, 0.f, 0.f, 0.f};
      #pragma unroll
      for (int kb = 0; kb < KB; ++kb)
        acc = __builtin_amdgcn_mfma_f32_16x16x32_bf16(afrag[mt][kb], bfrag[kb], acc, 0, 0, 0);
      #pragma unroll
      for (int r = 0; r < 4; ++r) {
        int node = m0 + mt * 16 + quad * 4 + r;
        if (node < n)
          H[(size_t)node * FOUT + ct * 16 + r16] = f2b(acc[r]);
      }
    }
  }
}

// OUT[g,:] = relu( sum_{e:dst=g} coef_e*H[src_e,:] + dinv[g]^2*H[g,:] + bias )
// F/8 lanes per node, 16B (8 bf16) per lane.
template<int F>
__global__ __launch_bounds__(256) void agg_kernel(const unsigned short* __restrict__ H,
    const int* __restrict__ row_ptr, const int* __restrict__ csr_src,
    const float* __restrict__ csr_coef, const float* __restrict__ dinv,
    const unsigned short* __restrict__ bias, unsigned short* __restrict__ OUT, int n) {
  constexpr int LPG = F / 8;
  constexpr int GPB = 256 / LPG;
  const int g = blockIdx.x * GPB + threadIdx.x / LPG;
  const int l = threadIdx.x % LPG;
  if (g >= n) return;
  const uint4* H4 = (const uint4*)H;
  float di = dinv[g];
  float c0 = di * di;
  uint4 hv = H4[(size_t)g * LPG + l];
  float a0 = b2f(hv.x & 0xffffu) * c0, a1 = b2f(hv.x >> 16) * c0;
  float a2 = b2f(hv.y & 0xffffu) * c0, a3 = b2f(hv.y >> 16) * c0;
  float a4 = b2f(hv.z & 0xffffu) * c0, a5 = b2f(hv.z >> 16) * c0;
  float a6 = b2f(hv.w & 0xffffu) * c0, a7 = b2f(hv.w >> 16) * c0;
  const int e1 = row_ptr[g + 1];
  for (int e = row_ptr[g]; e < e1; ++e) {
    int s = csr_src[e];
    float c = csr_coef[e];
    uint4 v = H4[(size_t)s * LPG + l];
    a0 = fmaf(b2f(v.x & 0xffffu), c, a0); a1 = fmaf(b2f(v.x >> 16), c, a1);
    a2 = fmaf(b2f(v.y & 0xffffu), c, a2); a3 = fmaf(b2f(v.y >> 16), c, a3);
    a4 = fmaf(b2f(v.z & 0xffffu), c, a4); a5 = fmaf(b2f(v.z >> 16), c, a5);
    a6 = fmaf(b2f(v.w & 0xffffu), c, a6); a7 = fmaf(b2f(v.w >> 16), c, a7);
  }
  uint4 bb = ((const uint4*)bias)[l];
  a0 += b2f(bb.x & 0xffffu); a1 += b2f(bb.x >> 16);
  a2 += b2f(bb.y & 0xffffu); a3 += b2f(bb.y >> 16);
  a4 += b2f(bb.z & 0xffffu); a5 += b2f(bb.z >> 16);
  a6 += b2f(bb.w & 0xffffu); a7 += b2f(bb.w >> 16);
  a0 = fmaxf(a0, 0.f); a1 = fmaxf(a1, 0.f); a2 = fmaxf(a2, 0.f); a3 = fmaxf(a3, 0.f);
  a4 = fmaxf(a4, 0.f); a5 = fmaxf(a5, 0.f); a6 = fmaxf(a6, 0.f); a7 = fmaxf(a7, 0.f);
  uint4 o;
  o.x = (unsigned int)f2b(a0) | ((unsigned int)f2b(a1) << 16);
  o.y = (unsigned int)f2b(a2) | ((unsigned int)f2b(a3) << 16);
  o.z = (unsigned int)f2b(a4) | ((unsigned int)f2b(a5) << 16);
  o.w = (unsigned int)f2b(a6) | ((unsigned int)f2b(a7) << 16);
  ((uint4*)OUT)[(size_t)g * LPG + l] = o;
}

__global__ __launch_bounds__(256) void pool_kernel(const unsigned short* __restrict__ X,
    const int* __restrict__ batch, float* __restrict__ pooled, float* __restrict__ cnt, int n) {
  __shared__ float acc[N_GRAPHS * 16];
  __shared__ float ccnt[N_GRAPHS];
  for (int i = threadIdx.x; i < N_GRAPHS * 16; i += 256) acc[i] = 0.f;
  if (threadIdx.x < N_GRAPHS) ccnt[threadIdx.x] = 0.f;
  __syncthreads();
  const int f = threadIdx.x & 15;
  const int lane = threadIdx.x >> 4;
  const int base = blockIdx.x * 256;
  for (int it = 0; it < 16; ++it) {
    int node = base + it * 16 + lane;
    if (node < n) {
      int g = batch[node];
      float v = b2f(X[(size_t)node * 16 + f]);
      atomicAdd(&acc[g * 16 + f], v);
      if (f == 0) atomicAdd(&ccnt[g], 1.f);
    }
  }
  __syncthreads();
  for (int i = threadIdx.x; i < N_GRAPHS * 16; i += 256)
    if (acc[i] != 0.f) atomicAdd(&pooled[i], acc[i]);
  if (threadIdx.x < N_GRAPHS && ccnt[threadIdx.x] != 0.f)
    atomicAdd(&cnt[threadIdx.x], ccnt[threadIdx.x]);
}

__global__ void final_kernel(const float* __restrict__ pooled, const float* __restrict__ cnt,
    const unsigned short* __restrict__ wc, void* __restrict__ out,
    const int* __restrict__ flags) {
  int id = blockIdx.x * blockDim.x + threadIdx.x;
  if (id >= N_GRAPHS * N_CLASSES) return;
  const unsigned short* Wlin = wc + WOFF[8];
  const unsigned short* blin = wc + WOFF[9];
  int g = id / N_CLASSES, c = id - g * N_CLASSES;
  float inv = 1.0f / fmaxf(cnt[g], 1.0f);
  float a = b2f(blin[c]);
  #pragma unroll
  for (int f = 0; f < 16; ++f)
    a = fmaf(pooled[g * 16 + f] * inv, b2f(Wlin[f * N_CLASSES + c]), a);
  if (flags[0]) ((float*)out)[id] = a;
  else          ((unsigned short*)out)[id] = f2b(a);
}

extern "C" void kernel_launch(void* const* d_in, const int* in_sizes, int n_in,
                              void* d_out, int out_size, void* d_ws, size_t ws_size,
                              hipStream_t stream) {
  const unsigned int* xraw = (const unsigned int*)d_in[0];
  const int* eraw          = (const int*)d_in[1];
  const int* braw          = (const int*)d_in[2];

  const int N = in_sizes[2];
  const int E = in_sizes[1] / 2;

  char* p = (char*)d_ws;
  auto alloc = [&](size_t bytes) -> void* {
    void* r = (void*)p;
    p += (bytes + 255) & ~(size_t)255;
    return r;
  };
  int*   flags    = (int*)  alloc(256);
  int*   deg      = (int*)  alloc((size_t)N * 4);
  int*   partials = (int*)  alloc(1024);               // ceil(N/256) <= 256
  int*   row_ptr  = (int*)  alloc((size_t)(N + 1) * 4);
  int*   cursor   = (int*)  alloc((size_t)N * 4);
  float* dinv     = (float*)alloc((size_t)N * 4);
  int*   src32    = (int*)  alloc((size_t)E * 4);
  int*   dst32    = (int*)  alloc((size_t)E * 4);
  int*   batch32  = (int*)  alloc((size_t)N * 4);
  int*   csr_src  = (int*)  alloc((size_t)E * 4);
  float* csr_coef = (float*)alloc((size_t)E * 4);
  unsigned short* wcan = (unsigned short*)alloc((size_t)WTOTAL * 2);
  unsigned short* xcan = (unsigned short*)alloc((size_t)N * FEAT * 2);
  unsigned short* hbuf = (unsigned short*)alloc((size_t)N * FEAT * 2);
  float* pooled = (float*)alloc(N_GRAPHS * 16 * 4);    // cntf allocated adjacent
  float* cntf   = (float*)alloc(N_GRAPHS * 4);

  hipMemsetAsync(deg, 0, (size_t)N * 4, stream);
  hipMemsetAsync(pooled, 0, (N_GRAPHS * 16 + 64) * 4, stream);  // pooled + pad + cntf region
  hipMemsetAsync(cntf, 0, N_GRAPHS * 4, stream);

  const int tb = 256;
  detect_kernel<<<1, 256, 0, stream>>>(xraw, (const unsigned int*)eraw, flags);

  int n2 = N * FEAT / 2;
  cvt_x_kernel<<<(n2 + tb - 1) / tb, tb, 0, stream>>>(xraw, (unsigned int*)xcan, braw, batch32, flags, n2, N);
  WPtrs wp;
  for (int i = 0; i < 10; ++i) wp.p[i] = d_in[3 + i];
  cvt_w_kernel<<<(WTOTAL + tb - 1) / tb, tb, 0, stream>>>(wp, wcan, flags);
  cvt_edges_kernel<<<(E + tb - 1) / tb, tb, 0, stream>>>(eraw, src32, dst32, deg, flags, E);

  int nb = (N + 255) / 256;
  scan1_kernel<<<nb, 256, 0, stream>>>(deg, partials, N);
  scan2_kernel<<<1, 256, 0, stream>>>(partials, nb);
  scan3_kernel<<<nb, 256, 0, stream>>>(deg, partials, row_ptr, cursor, dinv, N);
  fill_kernel<<<(E + tb - 1) / tb, tb, 0, stream>>>(src32, dst32, cursor, dinv, csr_src, csr_coef, E);

  const unsigned short* W1 = wcan + WOFF[0];
  const unsigned short* b1 = wcan + WOFF[1];
  const unsigned short* W2 = wcan + WOFF[2];
  const unsigned short* b2 = wcan + WOFF[3];
  const unsigned short* W3 = wcan + WOFF[4];
  const unsigned short* b3 = wcan + WOFF[5];
  const unsigned short* W4 = wcan + WOFF[6];
  const unsigned short* b4 = wcan + WOFF[7];

  const int gblocks = ((N + 31) / 32 + 3) / 4;  // 4 waves/block, 32 rows/wave

  // layer 1: 128 -> 128   (xcan -> hbuf -> xcan)
  mfma_gemm_kernel<128, 128><<<gblocks, 256, 0, stream>>>(xcan, W1, hbuf, N);
  agg_kernel<128><<<(N + 15) / 16, 256, 0, stream>>>(hbuf, row_ptr, csr_src, csr_coef, dinv, b1, xcan, N);
  // layer 2: 128 -> 64
  mfma_gemm_kernel<128, 64><<<gblocks, 256, 0, stream>>>(xcan, W2, hbuf, N);
  agg_kernel<64><<<(N + 31) / 32, 256, 0, stream>>>(hbuf, row_ptr, csr_src, csr_coef, dinv, b2, xcan, N);
  // layer 3: 64 -> 32
  mfma_gemm_kernel<64, 32><<<gblocks, 256, 0, stream>>>(xcan, W3, hbuf, N);
  agg_kernel<32><<<(N + 63) / 64, 256, 0, stream>>>(hbuf, row_ptr, csr_src, csr_coef, dinv, b3, xcan, N);
  // layer 4: 32 -> 16
  mfma_gemm_kernel<32, 16><<<gblocks, 256, 0, stream>>>(xcan, W4, hbuf, N);
  agg_kernel<16><<<(N + 127) / 128, 256, 0, stream>>>(hbuf, row_ptr, csr_src, csr_coef, dinv, b4, xcan, N);

  pool_kernel<<<(N + 255) / 256, 256, 0, stream>>>(xcan, batch32, pooled, cntf, N);
  final_kernel<<<(N_GRAPHS * N_CLASSES + 127) / 128, 128, 0, stream>>>(pooled, cntf, wcan, d_out, flags);
}

// Round 4
// 276.464 us; speedup vs baseline: 1.8115x; 1.1317x over previous
//
#include <hip/hip_runtime.h>
#include <hip/hip_bf16.h>

// GCN forward, MI355X. Dtype-detecting (fp32-vs-bf16 floats, int64-vs-int32
// indices), canonicalized into bf16/int32 workspace buffers.
//
// Round-4 structure:
//   detect -> cvt_all (x+batch | W->fragment-major | edges+deg, one kernel,
//   blockIdx-range split) -> 3-kernel scan -> fill (packed uint2 CSR, halves
//   HBM write amplification) -> 4x (LDS-free MFMA GEMM reading fragment-major
//   W straight from L2 -> agg with shfl-broadcast CSR) -> pool -> final.
//
// MFMA 16x16x32_bf16 layouts (verified m89/m91): A[m=l&15][k=(l>>4)*8+j]
// (k-contig -> 16B row-major loads); B frag f at Wf[f*1024 + l*16 .. +16]
// holds B[k=kb*32+(l>>4)*8+j][n=ct*16+(l&15)], f=ct*KB+kb; C/D col=l&15,
// row=(l>>4)*4+reg.

#define N_GRAPHS 64
#define N_CLASSES 10
static constexpr int FEAT = 128;

typedef short bf8_t __attribute__((ext_vector_type(8)));
typedef float f4_t  __attribute__((ext_vector_type(4)));

__device__ __forceinline__ float b2f(unsigned int u) {
  return __uint_as_float(u << 16);
}
__device__ __forceinline__ unsigned short f2b(float f) {
  unsigned int x = __float_as_uint(f);
  x += 0x7fffu + ((x >> 16) & 1u);   // RNE (finite values only)
  return (unsigned short)(x >> 16);
}

// flags[0]=1 if floats fp32 else bf16; flags[1]=1 if ints int64 else int32.
__global__ __launch_bounds__(256) void detect_kernel(const unsigned int* __restrict__ xraw,
    const unsigned int* __restrict__ eraw, int* __restrict__ flags) {
  __shared__ int cnt_bf16, cnt_i64nz;
  if (threadIdx.x == 0) { cnt_bf16 = 0; cnt_i64nz = 0; }
  __syncthreads();
  unsigned int d = xraw[threadIdx.x];
  int e = (int)(((d & 0xffffu) >> 7) & 0xff);
  if (e >= 100 && e <= 140) atomicAdd(&cnt_bf16, 1);
  if (threadIdx.x < 64 && eraw[2 * threadIdx.x + 1] != 0u) atomicAdd(&cnt_i64nz, 1);
  __syncthreads();
  if (threadIdx.x == 0) {
    flags[0] = (cnt_bf16 < 150) ? 1 : 0;
    flags[1] = (cnt_i64nz == 0) ? 1 : 0;
  }
}

struct WPtrs { const void* p[10]; };
static constexpr int WSEG[10] = {16384, 128, 8192, 64, 2048, 32, 512, 16, 160, 10};
static constexpr int WTOTAL   = 27546;
static constexpr int WOFF[10] = {0, 16384, 16512, 24704, 24768, 26816, 26848, 27360, 27376, 27536};

// One kernel, three block ranges: [0,BX) x+batch convert; [BX,BX+BW) weight
// convert (W1..W4 written fragment-major); rest: edge convert + degree count.
__global__ __launch_bounds__(256) void cvt_all_kernel(
    const unsigned int* __restrict__ xraw, unsigned int* __restrict__ xc,
    const int* __restrict__ braw, int* __restrict__ b32,
    WPtrs wp, unsigned short* __restrict__ wc,
    const int* __restrict__ eraw, int* __restrict__ src32, int* __restrict__ dst32,
    int* __restrict__ deg, const int* __restrict__ flags,
    int BX, int BW, int n2, int n, int E) {
  const int bid = blockIdx.x;
  if (bid < BX) {
    int i = bid * 256 + threadIdx.x;
    if (i < n2) {
      if (flags[0]) {
        const float* xf = (const float*)xraw;
        xc[i] = (unsigned int)f2b(xf[2 * i]) | ((unsigned int)f2b(xf[2 * i + 1]) << 16);
      } else {
        xc[i] = xraw[i];
      }
    }
    if (i < n) b32[i] = flags[1] ? braw[2 * i] : braw[i];
  } else if (bid < BX + BW) {
    int i = (bid - BX) * 256 + threadIdx.x;
    if (i >= WTOTAL) return;
    int off = i, s = 0;
    #pragma unroll
    for (int t = 0; t < 10; ++t) {
      if (s == 0 && off >= WSEG[t]) { off -= WSEG[t]; } else if (s == 0) { s = t + 1; }
    }
    s -= 1;
    int soff = off;
    if ((s & 1) == 0 && s <= 6) {           // W1..W4: fragment-major transform
      int KB, FOUT;
      if (s == 0)      { KB = 4; FOUT = 128; }
      else if (s == 2) { KB = 4; FOUT = 64; }
      else if (s == 4) { KB = 2; FOUT = 32; }
      else             { KB = 1; FOUT = 16; }
      int j = off & 7, l = (off >> 3) & 63, f = off >> 9;
      int ct = f / KB, kb = f - ct * KB;
      int k = kb * 32 + ((l >> 4) << 3) + j;
      int nn = ct * 16 + (l & 15);
      soff = k * FOUT + nn;
    }
    const void* p = wp.p[s];
    wc[WOFF[s] + off] = flags[0] ? f2b(((const float*)p)[soff])
                                 : ((const unsigned short*)p)[soff];
  } else {
    int e = (bid - BX - BW) * 256 + threadIdx.x;
    if (e >= E) return;
    int s, d;
    if (flags[1]) { s = eraw[2 * e]; d = eraw[2 * (E + e)]; }
    else          { s = eraw[e];     d = eraw[E + e]; }
    src32[e] = s; dst32[e] = d;
    atomicAdd(&deg[d], 1);
  }
}

// ---- hierarchical scan: deg -> row_ptr/cursor/dinv ----
__device__ __forceinline__ int block_incl_scan(int v, int* wave_sums) {
  const int lane = threadIdx.x & 63;
  const int wv = threadIdx.x >> 6;
  int x = v;
  #pragma unroll
  for (int off = 1; off < 64; off <<= 1) {
    int y = __shfl_up(x, off, 64);
    if (lane >= off) x += y;
  }
  if (lane == 63) wave_sums[wv] = x;
  __syncthreads();
  int wbase = 0;
  for (int w = 0; w < wv; ++w) wbase += wave_sums[w];
  return x + wbase;
}

__global__ __launch_bounds__(256) void scan1_kernel(const int* __restrict__ deg,
    int* __restrict__ partials, int n) {
  __shared__ int ws[4];
  int i = blockIdx.x * 256 + threadIdx.x;
  int v = (i < n) ? deg[i] : 0;
  int incl = block_incl_scan(v, ws);
  if (threadIdx.x == 255) partials[blockIdx.x] = incl;
}

__global__ __launch_bounds__(256) void scan2_kernel(int* __restrict__ partials, int nb) {
  __shared__ int ws[4];
  int v = (threadIdx.x < nb) ? partials[threadIdx.x] : 0;
  int incl = block_incl_scan(v, ws);
  if (threadIdx.x < nb) partials[threadIdx.x] = incl - v;  // exclusive
}

__global__ __launch_bounds__(256) void scan3_kernel(const int* __restrict__ deg,
    const int* __restrict__ partials, int* __restrict__ row_ptr, int* __restrict__ cursor,
    float* __restrict__ dinv, int n) {
  __shared__ int ws[4];
  int i = blockIdx.x * 256 + threadIdx.x;
  int v = (i < n) ? deg[i] : 0;
  int incl = block_incl_scan(v, ws) + partials[blockIdx.x];
  if (i < n) {
    row_ptr[i + 1] = incl;
    cursor[i] = incl - v;
    dinv[i] = rsqrtf((float)v + 1.0f);
  }
  if (i == 0) row_ptr[0] = 0;
}

// Packed CSR: one uint2 (src, coef bits) per edge -> one 8B store, half the
// dirty-line writeback of two 4B arrays.
__global__ void fill_kernel(const int* __restrict__ src, const int* __restrict__ dst,
    int* __restrict__ cursor, const float* __restrict__ dinv,
    uint2* __restrict__ csr, int E) {
  int e = blockIdx.x * blockDim.x + threadIdx.x;
  if (e < E) {
    int s = src[e], d = dst[e];
    int pos = atomicAdd(&cursor[d], 1);
    uint2 v;
    v.x = (unsigned int)s;
    v.y = __float_as_uint(dinv[s] * dinv[d]);
    csr[pos] = v;
  }
}

// H[n,FOUT] = X[n,FIN] @ W[FIN,FOUT] via v_mfma_f32_16x16x32_bf16.
// Wave = 32 rows; B fragments loaded as contiguous 16B from fragment-major
// Wf (L1/L2-hot). No LDS, no barriers.
template<int FIN, int FOUT>
__global__ __launch_bounds__(256) void mfma_gemm_kernel(const unsigned short* __restrict__ X,
    const unsigned short* __restrict__ Wf, unsigned short* __restrict__ H, int n) {
  constexpr int KB = FIN / 32;
  constexpr int CT = FOUT / 16;
  const int l = threadIdx.x & 63;
  const int r16 = l & 15, quad = l >> 4;
  const int m0 = (blockIdx.x * 4 + (threadIdx.x >> 6)) * 32;
  if (m0 >= n) return;
  bf8_t afrag[2][KB];
  #pragma unroll
  for (int mt = 0; mt < 2; ++mt) {
    int node = m0 + mt * 16 + r16;
    int nc = node < n ? node : n - 1;
    const unsigned short* xp = X + (size_t)nc * FIN + quad * 8;
    #pragma unroll
    for (int kb = 0; kb < KB; ++kb)
      afrag[mt][kb] = *(const bf8_t*)(xp + kb * 32);
  }
  #pragma unroll
  for (int ct = 0; ct < CT; ++ct) {
    bf8_t bfrag[KB];
    #pragma unroll
    for (int kb = 0; kb < KB; ++kb)
      bfrag[kb] = *(const bf8_t*)(Wf + ((ct * KB + kb) * 64 + l) * 8);
    #pragma unroll
    for (int mt = 0; mt < 2; ++mt) {
      f4_t acc = {0.f, 0.f, 0.f, 0.f};
      #pragma unroll
      for (int kb = 0; kb < KB; ++kb)
        acc = __builtin_amdgcn_mfma_f32_16x16x32_bf16(afrag[mt][kb], bfrag[kb], acc, 0, 0, 0);
      #pragma unroll
      for (int r = 0; r < 4; ++r) {
        int node = m0 + mt * 16 + quad * 4 + r;
        if (node < n)
          H[(size_t)node * FOUT + ct * 16 + r16] = f2b(acc[r]);
      }
    }
  }
}

// OUT[g,:] = relu( sum_{e:dst=g} coef_e*H[src_e,:] + dinv[g]^2*H[g,:] + bias )
// F/8 lanes per node, 16B/lane. CSR entries batch-loaded LPG at a time and
// shfl-broadcast so the inner loop's only memory dependency is the H gather.
template<int F>
__global__ __launch_bounds__(256) void agg_kernel(const unsigned short* __restrict__ H,
    const int* __restrict__ row_ptr, const uint2* __restrict__ csr,
    const float* __restrict__ dinv,
    const unsigned short* __restrict__ bias, unsigned short* __restrict__ OUT, int n) {
  constexpr int LPG = F / 8;
  constexpr int GPB = 256 / LPG;
  const int g = blockIdx.x * GPB + threadIdx.x / LPG;
  const int l = threadIdx.x % LPG;
  if (g >= n) return;
  const uint4* H4 = (const uint4*)H;
  float di = dinv[g];
  float c0 = di * di;
  uint4 hv = H4[(size_t)g * LPG + l];
  float a0 = b2f(hv.x & 0xffffu) * c0, a1 = b2f(hv.x >> 16) * c0;
  float a2 = b2f(hv.y & 0xffffu) * c0, a3 = b2f(hv.y >> 16) * c0;
  float a4 = b2f(hv.z & 0xffffu) * c0, a5 = b2f(hv.z >> 16) * c0;
  float a6 = b2f(hv.w & 0xffffu) * c0, a7 = b2f(hv.w >> 16) * c0;
  const int e0 = row_ptr[g], e1 = row_ptr[g + 1];
  for (int base = e0; base < e1; base += LPG) {
    int cnt = e1 - base < LPG ? e1 - base : LPG;
    uint2 my = csr[(base + l < e1) ? (base + l) : (e1 - 1)];
    for (int j = 0; j < cnt; ++j) {
      int s = __shfl((int)my.x, j, LPG);
      float c = __uint_as_float(__shfl((int)my.y, j, LPG));
      uint4 v = H4[(size_t)s * LPG + l];
      a0 = fmaf(b2f(v.x & 0xffffu), c, a0); a1 = fmaf(b2f(v.x >> 16), c, a1);
      a2 = fmaf(b2f(v.y & 0xffffu), c, a2); a3 = fmaf(b2f(v.y >> 16), c, a3);
      a4 = fmaf(b2f(v.z & 0xffffu), c, a4); a5 = fmaf(b2f(v.z >> 16), c, a5);
      a6 = fmaf(b2f(v.w & 0xffffu), c, a6); a7 = fmaf(b2f(v.w >> 16), c, a7);
    }
  }
  uint4 bb = ((const uint4*)bias)[l];
  a0 += b2f(bb.x & 0xffffu); a1 += b2f(bb.x >> 16);
  a2 += b2f(bb.y & 0xffffu); a3 += b2f(bb.y >> 16);
  a4 += b2f(bb.z & 0xffffu); a5 += b2f(bb.z >> 16);
  a6 += b2f(bb.w & 0xffffu); a7 += b2f(bb.w >> 16);
  a0 = fmaxf(a0, 0.f); a1 = fmaxf(a1, 0.f); a2 = fmaxf(a2, 0.f); a3 = fmaxf(a3, 0.f);
  a4 = fmaxf(a4, 0.f); a5 = fmaxf(a5, 0.f); a6 = fmaxf(a6, 0.f); a7 = fmaxf(a7, 0.f);
  uint4 o;
  o.x = (unsigned int)f2b(a0) | ((unsigned int)f2b(a1) << 16);
  o.y = (unsigned int)f2b(a2) | ((unsigned int)f2b(a3) << 16);
  o.z = (unsigned int)f2b(a4) | ((unsigned int)f2b(a5) << 16);
  o.w = (unsigned int)f2b(a6) | ((unsigned int)f2b(a7) << 16);
  ((uint4*)OUT)[(size_t)g * LPG + l] = o;
}

__global__ __launch_bounds__(256) void pool_kernel(const unsigned short* __restrict__ X,
    const int* __restrict__ batch, float* __restrict__ pooled, float* __restrict__ cnt, int n) {
  __shared__ float acc[N_GRAPHS * 16];
  __shared__ float ccnt[N_GRAPHS];
  for (int i = threadIdx.x; i < N_GRAPHS * 16; i += 256) acc[i] = 0.f;
  if (threadIdx.x < N_GRAPHS) ccnt[threadIdx.x] = 0.f;
  __syncthreads();
  const int f = threadIdx.x & 15;
  const int lane = threadIdx.x >> 4;
  const int base = blockIdx.x * 256;
  for (int it = 0; it < 16; ++it) {
    int node = base + it * 16 + lane;
    if (node < n) {
      int g = batch[node];
      float v = b2f(X[(size_t)node * 16 + f]);
      atomicAdd(&acc[g * 16 + f], v);
      if (f == 0) atomicAdd(&ccnt[g], 1.f);
    }
  }
  __syncthreads();
  for (int i = threadIdx.x; i < N_GRAPHS * 16; i += 256)
    if (acc[i] != 0.f) atomicAdd(&pooled[i], acc[i]);
  if (threadIdx.x < N_GRAPHS && ccnt[threadIdx.x] != 0.f)
    atomicAdd(&cnt[threadIdx.x], ccnt[threadIdx.x]);
}

__global__ void final_kernel(const float* __restrict__ pooled, const float* __restrict__ cnt,
    const unsigned short* __restrict__ wc, void* __restrict__ out,
    const int* __restrict__ flags) {
  int id = blockIdx.x * blockDim.x + threadIdx.x;
  if (id >= N_GRAPHS * N_CLASSES) return;
  const unsigned short* Wlin = wc + WOFF[8];
  const unsigned short* blin = wc + WOFF[9];
  int g = id / N_CLASSES, c = id - g * N_CLASSES;
  float inv = 1.0f / fmaxf(cnt[g], 1.0f);
  float a = b2f(blin[c]);
  #pragma unroll
  for (int f = 0; f < 16; ++f)
    a = fmaf(pooled[g * 16 + f] * inv, b2f(Wlin[f * N_CLASSES + c]), a);
  if (flags[0]) ((float*)out)[id] = a;
  else          ((unsigned short*)out)[id] = f2b(a);
}

extern "C" void kernel_launch(void* const* d_in, const int* in_sizes, int n_in,
                              void* d_out, int out_size, void* d_ws, size_t ws_size,
                              hipStream_t stream) {
  const unsigned int* xraw = (const unsigned int*)d_in[0];
  const int* eraw          = (const int*)d_in[1];
  const int* braw          = (const int*)d_in[2];

  const int N = in_sizes[2];
  const int E = in_sizes[1] / 2;

  char* p = (char*)d_ws;
  auto alloc = [&](size_t bytes) -> void* {
    void* r = (void*)p;
    p += (bytes + 255) & ~(size_t)255;
    return r;
  };
  int*   flags    = (int*)  alloc(256);
  int*   deg      = (int*)  alloc((size_t)N * 4);
  int*   partials = (int*)  alloc(1024);
  int*   row_ptr  = (int*)  alloc((size_t)(N + 1) * 4);
  int*   cursor   = (int*)  alloc((size_t)N * 4);
  float* dinv     = (float*)alloc((size_t)N * 4);
  int*   src32    = (int*)  alloc((size_t)E * 4);
  int*   dst32    = (int*)  alloc((size_t)E * 4);
  int*   batch32  = (int*)  alloc((size_t)N * 4);
  uint2* csr      = (uint2*)alloc((size_t)E * 8);
  unsigned short* wcan = (unsigned short*)alloc((size_t)WTOTAL * 2);
  unsigned short* xcan = (unsigned short*)alloc((size_t)N * FEAT * 2);
  unsigned short* hbuf = (unsigned short*)alloc((size_t)N * FEAT * 2);
  float* pooled = (float*)alloc(N_GRAPHS * 16 * 4);
  float* cntf   = (float*)alloc(N_GRAPHS * 4);

  hipMemsetAsync(deg, 0, (size_t)N * 4, stream);
  hipMemsetAsync(pooled, 0, N_GRAPHS * 16 * 4, stream);
  hipMemsetAsync(cntf, 0, N_GRAPHS * 4, stream);

  const int tb = 256;
  detect_kernel<<<1, 256, 0, stream>>>(xraw, (const unsigned int*)eraw, flags);

  const int n2 = N * FEAT / 2;
  const int BX = (n2 + 255) / 256;
  const int BW = (WTOTAL + 255) / 256;
  const int BE = (E + 255) / 256;
  WPtrs wp;
  for (int i = 0; i < 10; ++i) wp.p[i] = d_in[3 + i];
  cvt_all_kernel<<<BX + BW + BE, 256, 0, stream>>>(xraw, (unsigned int*)xcan,
      braw, batch32, wp, wcan, eraw, src32, dst32, deg, flags, BX, BW, n2, N, E);

  const int nb = (N + 255) / 256;
  scan1_kernel<<<nb, 256, 0, stream>>>(deg, partials, N);
  scan2_kernel<<<1, 256, 0, stream>>>(partials, nb);
  scan3_kernel<<<nb, 256, 0, stream>>>(deg, partials, row_ptr, cursor, dinv, N);
  fill_kernel<<<(E + tb - 1) / tb, tb, 0, stream>>>(src32, dst32, cursor, dinv, csr, E);

  const unsigned short* W1 = wcan + WOFF[0];
  const unsigned short* b1 = wcan + WOFF[1];
  const unsigned short* W2 = wcan + WOFF[2];
  const unsigned short* b2 = wcan + WOFF[3];
  const unsigned short* W3 = wcan + WOFF[4];
  const unsigned short* b3 = wcan + WOFF[5];
  const unsigned short* W4 = wcan + WOFF[6];
  const unsigned short* b4 = wcan + WOFF[7];

  const int gblocks = ((N + 31) / 32 + 3) / 4;

  mfma_gemm_kernel<128, 128><<<gblocks, 256, 0, stream>>>(xcan, W1, hbuf, N);
  agg_kernel<128><<<(N + 15) / 16, 256, 0, stream>>>(hbuf, row_ptr, csr, dinv, b1, xcan, N);
  mfma_gemm_kernel<128, 64><<<gblocks, 256, 0, stream>>>(xcan, W2, hbuf, N);
  agg_kernel<64><<<(N + 31) / 32, 256, 0, stream>>>(hbuf, row_ptr, csr, dinv, b2, xcan, N);
  mfma_gemm_kernel<64, 32><<<gblocks, 256, 0, stream>>>(xcan, W3, hbuf, N);
  agg_kernel<32><<<(N + 63) / 64, 256, 0, stream>>>(hbuf, row_ptr, csr, dinv, b3, xcan, N);
  mfma_gemm_kernel<32, 16><<<gblocks, 256, 0, stream>>>(xcan, W4, hbuf, N);
  agg_kernel<16><<<(N + 127) / 128, 256, 0, stream>>>(hbuf, row_ptr, csr, dinv, b4, xcan, N);

  pool_kernel<<<(N + 255) / 256, 256, 0, stream>>>(xcan, batch32, pooled, cntf, N);
  final_kernel<<<(N_GRAPHS * N_CLASSES + 127) / 128, 128, 0, stream>>>(pooled, cntf, wcan, d_out, flags);
}